// Round 7
// baseline (258.052 us; speedup 1.0000x reference)
//
#include <hip/hip_runtime.h>

// LIF constants (match reference); K = exp(-1/20)
#define KOEFF 0.951229424500714f
#define KP2   0.904837418035960f   // K^2
#define KP4   0.818730753077982f   // K^4
#define KP8   0.670320046035639f   // K^8
#define KP16  0.449328964117222f   // K^16
#define K64   0.040762203978366f   // K^64
#define LOG2K (-0.07213475204444817f) // log2(K)

typedef unsigned short u16;
typedef __attribute__((ext_vector_type(8))) short short8;   // 8 bf16 (MFMA A/B frag)
typedef __attribute__((ext_vector_type(4))) float f32x4;    // MFMA C/D frag

__device__ __forceinline__ u16 f2bf(float f) {
  unsigned int v = __float_as_uint(f);
  unsigned int r = (v + 0x7FFFu + ((v >> 16) & 1u)) >> 16;
  return (u16)r;
}

// ---------------------------------------------------------------------------
// Kernel 1 (merged prep): blockIdx.x partitions two independent jobs:
//   [0,4096)    : X [64][512 j][512 t] fp32 -> XT16 [64][512 t][512 j] bf16
//   [4096,7168) : W rows 512..2047 cols 0..511 -> bf16 Whi[1536][512]; zero flags
// ---------------------------------------------------------------------------
__global__ __launch_bounds__(256) void k_prep(const float* __restrict__ X, const float* __restrict__ W,
                                              u16* __restrict__ XT, u16* __restrict__ Whi,
                                              int* __restrict__ flags) {
  __shared__ float tile[64][65];
  const int blk = blockIdx.x;
  if (blk < 4096) {
    const int b  = blk >> 6;
    const int r2 = blk & 63;
    const int j0 = (r2 & 7) * 64;
    const int t0 = (r2 >> 3) * 64;
    const float* src = X + ((size_t)b * 512 + j0) * 512 + t0;
    for (int e = threadIdx.x; e < 64 * 16; e += 256) {
      int r = e >> 4, c = e & 15;
      float4 v = *(const float4*)(src + (size_t)r * 512 + c * 4);
      tile[r][c * 4 + 0] = v.x; tile[r][c * 4 + 1] = v.y;
      tile[r][c * 4 + 2] = v.z; tile[r][c * 4 + 3] = v.w;
    }
    __syncthreads();
    u16* dst = XT + ((size_t)b * 512 + t0) * 512 + j0;
    for (int e = threadIdx.x; e < 64 * 16; e += 256) {
      int tr = e >> 4, c = e & 15;
      ushort4 o;
      o.x = f2bf(tile[c * 4 + 0][tr]); o.y = f2bf(tile[c * 4 + 1][tr]);
      o.z = f2bf(tile[c * 4 + 2][tr]); o.w = f2bf(tile[c * 4 + 3][tr]);
      *(ushort4*)(dst + (size_t)tr * 512 + c * 4) = o;
    }
  } else {
    if (blk == 4096 && threadIdx.x < 64) flags[threadIdx.x] = 0;
    int p = (blk - 4096) * 256 + threadIdx.x;   // exactly covers 1536*512
    int i = p >> 9, j = p & 511;
    Whi[p] = f2bf(W[(size_t)(512 + i) * 2048 + j]);
  }
}

// ---------------------------------------------------------------------------
// Kernel 2 (fused GEMM + chunk-scan): block (mt, b) computes 128 neurons x
// 512 t. 1024 threads = 16 waves = 2 m-halves x 8 chunks; per-wave tile
// 64 n x 64 t (acc 4x4 f32x4). 2-phase K-loop (BK=64), XOR-swizzled LDS
// (pre-swizzled global source, rule #21).
// After the GEMM: weighted Kogge-Stone prefix scan over t IN REGISTERS
// (K^D shfl_up rounds + ni-block combine), 4 KB LDS P-exchange for the
// cross-chunk affine carry, spike thresholding + output store, viol flag.
// Exact while no spike/clamp occurs anywhere (backstop: k_fix).
// ---------------------------------------------------------------------------
__global__ __launch_bounds__(1024) void k_fused(const u16* __restrict__ A, const u16* __restrict__ Bx,
                                                float* __restrict__ out, int* __restrict__ flags) {
  __shared__ u16 lA[128 * 64];
  __shared__ u16 lB[512 * 64];
  __shared__ float Pl[8 * 128];
  const int mt   = blockIdx.x;     // 0..11 (neuron tile)
  const int b    = blockIdx.y;     // batch
  const int tid  = threadIdx.x;
  const int wv   = tid >> 6;       // 0..15
  const int lane = tid & 63;
  const int tl   = lane & 15;      // t within 16-block
  const int qg   = lane >> 4;      // 0..3 (neuron quad group)
  const int l7   = lane & 7;
  const int c    = wv & 7;         // wave's time chunk (64 t)
  const int h    = wv >> 3;        // wave's m-half (64 neurons)

  f32x4 acc[4][4];
#pragma unroll
  for (int mi = 0; mi < 4; ++mi)
#pragma unroll
    for (int ni = 0; ni < 4; ++ni) acc[mi][ni] = (f32x4)0.0f;

  const u16* gA = A + (size_t)mt * 128 * 512;
  const u16* gB = Bx + (size_t)b * 512 * 512;

  // staging offsets (pre-swizzled source; linear LDS dest)
  const int r    = tid >> 3;                       // 0..127
  const int kc   = tid & 7;
  const int soff = r * 512 + ((kc ^ (r & 7)) << 3);  // elems

  for (int k0 = 0; k0 < 512; k0 += 64) {
    __syncthreads();   // all waves done reading previous tile
    __builtin_amdgcn_global_load_lds(
        (const __attribute__((address_space(1))) void*)(gA + soff + k0),
        (__attribute__((address_space(3))) void*)(lA + wv * 512), 16, 0, 0);
#pragma unroll
    for (int it = 0; it < 4; ++it) {
      __builtin_amdgcn_global_load_lds(
          (const __attribute__((address_space(1))) void*)(gB + it * 65536 + soff + k0),
          (__attribute__((address_space(3))) void*)(lB + it * 8192 + wv * 512), 16, 0, 0);
    }
    __syncthreads();   // implies vmcnt(0): LDS tile ready
#pragma unroll
    for (int ks = 0; ks < 2; ++ks) {
      short8 ah[4], bb[4];
      const int kx = (((ks << 2) | qg) ^ l7) << 3;
#pragma unroll
      for (int mi = 0; mi < 4; ++mi)
        ah[mi] = *(const short8*)&lA[(h * 64 + mi * 16 + tl) * 64 + kx];
#pragma unroll
      for (int ni = 0; ni < 4; ++ni)
        bb[ni] = *(const short8*)&lB[(c * 64 + ni * 16 + tl) * 64 + kx];
#pragma unroll
      for (int mi = 0; mi < 4; ++mi)
#pragma unroll
        for (int ni = 0; ni < 4; ++ni)
          acc[mi][ni] = __builtin_amdgcn_mfma_f32_16x16x32_bf16(ah[mi], bb[ni], acc[mi][ni], 0, 0, 0);
    }
  }
  __syncthreads();

  // --- S1: weighted Kogge-Stone inclusive scan within each 16-lane t-group.
  // After this, acc[mi][ni][q] = sum_{tau<=tl} K^{tl-tau} u(tau) within its block of 16.
  {
    const float kd[4] = {KOEFF, KP2, KP4, KP8};
    const int   dd[4] = {1, 2, 4, 8};
#pragma unroll
    for (int rd = 0; rd < 4; ++rd) {
      const float kw = kd[rd];
      const int   dl = dd[rd];
#pragma unroll
      for (int mi = 0; mi < 4; ++mi)
#pragma unroll
        for (int ni = 0; ni < 4; ++ni) {
#pragma unroll
          for (int q = 0; q < 4; ++q) {
            float g = __shfl_up(acc[mi][ni][q], dl, 16);
            if (tl < dl) g = 0.f;
            acc[mi][ni][q] = fmaf(kw, g, acc[mi][ni][q]);
          }
        }
    }
  }

  // --- S2: per-neuron chunk totals -> Pl[c][n]  (P = sum_{tau=0..63} K^{63-tau} u)
#pragma unroll
  for (int mi = 0; mi < 4; ++mi)
#pragma unroll
    for (int q = 0; q < 4; ++q) {
      float b0 = __shfl(acc[mi][0][q], 15, 16);
      float b1 = __shfl(acc[mi][1][q], 15, 16);
      float b2 = __shfl(acc[mi][2][q], 15, 16);
      float b3 = __shfl(acc[mi][3][q], 15, 16);
      float T = fmaf(fmaf(fmaf(b0, KP16, b1), KP16, b2), KP16, b3);
      if (tl == 0) Pl[c * 128 + h * 64 + mi * 16 + qg * 4 + q] = T;
    }
  __syncthreads();

  // --- S3+S4: chunk-start carry from Pl, then final states + spikes.
  const float kp = KOEFF * exp2f(LOG2K * (float)tl);   // K^{tl+1}
  const bool isout = (mt >= 10);                       // neurons i' >= 1280
  bool viol = false;
#pragma unroll
  for (int mi = 0; mi < 4; ++mi) {
#pragma unroll
    for (int q = 0; q < 4; ++q) {
      const int nl = h * 64 + mi * 16 + qg * 4 + q;    // neuron within 128
      float cr = 0.f;
      for (int d = 0; d < c; ++d) cr = fmaf(cr, K64, Pl[d * 128 + nl]);
      // cr = s at chunk start; walk the 4 ni-blocks
      const int gn = mt * 128 + nl;                    // global i'
#pragma unroll
      for (int ni = 0; ni < 4; ++ni) {
        float S = fmaf(kp, cr, acc[mi][ni][q]);
        bool sp = (S >= 1.0f);
        viol = viol || sp || (S < -1.0f);
        if (isout)
          out[((size_t)b * 256 + (gn - 1280)) * 512 + c * 64 + ni * 16 + tl] = sp ? 1.f : 0.f;
        cr = __shfl(S, 15, 16);
      }
    }
  }
  if (viol) atomicOr(&flags[b], 1);
}

// ---------------------------------------------------------------------------
// Kernel 3: exact backstop, gated per batch on spike flag. Simulates the full
// LIF dynamics (with recurrence/refractory/clamp) from X and W directly.
// Expected: immediate exit for all batches.
// ---------------------------------------------------------------------------
__global__ __launch_bounds__(256) void k_fix(const float* __restrict__ X, const float* __restrict__ W,
                                             const int* __restrict__ flags, float* __restrict__ out) {
  const int b = blockIdx.x;
  if (flags[b] == 0) return;   // uniform per block
  const int tid = threadIdx.x;
  const int wv = tid >> 6, lane = tid & 63;
  float st[6], rf[6];
#pragma unroll
  for (int r = 0; r < 6; ++r) { st[r] = 0.f; rf[r] = 0.f; }
  __shared__ unsigned int mask[64];
  for (int w = tid; w < 64; w += 256) mask[w] = 0u;
  __syncthreads();
  for (int t = 0; t < 512; ++t) {
    {
      float x = X[((size_t)b * 512 + tid) * 512 + t];
      unsigned long long bl = __ballot(x > 0.5f);
      if (lane == 0) { mask[2 * wv] = (unsigned int)bl; mask[2 * wv + 1] = (unsigned int)(bl >> 32); }
      x = X[((size_t)b * 512 + 256 + tid) * 512 + t];
      bl = __ballot(x > 0.5f);
      if (lane == 0) { mask[8 + 2 * wv] = (unsigned int)bl; mask[9 + 2 * wv] = (unsigned int)(bl >> 32); }
    }
    __syncthreads();
    float add[6] = {0.f, 0.f, 0.f, 0.f, 0.f, 0.f};
    for (int wd = 0; wd < 64; ++wd) {
      unsigned int m = mask[wd];
      while (m) {
        int bitp = __ffs(m) - 1;
        m &= m - 1;
        int j = wd * 32 + bitp;
#pragma unroll
        for (int r = 0; r < 6; ++r) add[r] += W[(size_t)(512 + tid + 256 * r) * 2048 + j];
      }
    }
    bool sp[6];
#pragma unroll
    for (int r = 0; r < 6; ++r) {
      float a = fmaf(st[r], KOEFF, add[r]);
      if (rf[r] > 0.f) a = 0.f;
      sp[r] = a >= 1.0f;
      rf[r] -= 1.f;
      if (sp[r]) rf[r] = 2.f;
      if (a < -1.f) a = -1.f;
      st[r] = a;
      int gi = 512 + tid + 256 * r;
      if (gi >= 1792) out[((size_t)b * 256 + (gi - 1792)) * 512 + t] = sp[r] ? 1.f : 0.f;
    }
    __syncthreads();
#pragma unroll
    for (int r = 0; r < 6; ++r) {
      unsigned long long bl = __ballot(sp[r]);
      if (lane == 0) {
        mask[16 + 8 * r + 2 * wv] = (unsigned int)bl;
        mask[17 + 8 * r + 2 * wv] = (unsigned int)(bl >> 32);
      }
    }
    __syncthreads();
  }
}

// ---------------------------------------------------------------------------
// Fallback exact simulator (ungated; used when ws too small for fast path)
// ---------------------------------------------------------------------------
__global__ __launch_bounds__(256) void k_exact(const float* __restrict__ X, const float* __restrict__ W,
                                               float* __restrict__ out) {
  const int b = blockIdx.x, tid = threadIdx.x;
  const int wv = tid >> 6, lane = tid & 63;
  float st[6], rf[6];
#pragma unroll
  for (int r = 0; r < 6; ++r) { st[r] = 0.f; rf[r] = 0.f; }
  __shared__ unsigned int mask[64];
  for (int w = tid; w < 64; w += 256) mask[w] = 0u;
  __syncthreads();
  for (int t = 0; t < 512; ++t) {
    {
      float x = X[((size_t)b * 512 + tid) * 512 + t];
      unsigned long long bl = __ballot(x > 0.5f);
      if (lane == 0) { mask[2 * wv] = (unsigned int)bl; mask[2 * wv + 1] = (unsigned int)(bl >> 32); }
      x = X[((size_t)b * 512 + 256 + tid) * 512 + t];
      bl = __ballot(x > 0.5f);
      if (lane == 0) { mask[8 + 2 * wv] = (unsigned int)bl; mask[9 + 2 * wv] = (unsigned int)(bl >> 32); }
    }
    __syncthreads();
    float add[6] = {0.f, 0.f, 0.f, 0.f, 0.f, 0.f};
    for (int wd = 0; wd < 64; ++wd) {
      unsigned int m = mask[wd];
      while (m) {
        int bitp = __ffs(m) - 1;
        m &= m - 1;
        int j = wd * 32 + bitp;
#pragma unroll
        for (int r = 0; r < 6; ++r) add[r] += W[(size_t)(512 + tid + 256 * r) * 2048 + j];
      }
    }
    bool sp[6];
#pragma unroll
    for (int r = 0; r < 6; ++r) {
      float a = fmaf(st[r], KOEFF, add[r]);
      if (rf[r] > 0.f) a = 0.f;
      sp[r] = a >= 1.0f;
      rf[r] -= 1.f;
      if (sp[r]) rf[r] = 2.f;
      if (a < -1.f) a = -1.f;
      st[r] = a;
      int gi = 512 + tid + 256 * r;
      if (gi >= 1792) out[((size_t)b * 256 + (gi - 1792)) * 512 + t] = sp[r] ? 1.f : 0.f;
    }
    __syncthreads();
#pragma unroll
    for (int r = 0; r < 6; ++r) {
      unsigned long long bl = __ballot(sp[r]);
      if (lane == 0) {
        mask[16 + 8 * r + 2 * wv] = (unsigned int)bl;
        mask[17 + 8 * r + 2 * wv] = (unsigned int)(bl >> 32);
      }
    }
    __syncthreads();
  }
}

// ---------------------------------------------------------------------------
extern "C" void kernel_launch(void* const* d_in, const int* in_sizes, int n_in,
                              void* d_out, int out_size, void* d_ws, size_t ws_size,
                              hipStream_t stream) {
  const float* X = (const float*)d_in[0];   // [64][512][512]
  const float* W = (const float*)d_in[1];   // [2048][2048]
  float* out = (float*)d_out;               // [64][256][512]
  char* ws = (char*)d_ws;

  const size_t SZ_XT = 64ull * 512 * 512 * 2;   // 33,554,432
  const size_t SZ_WH = 1536ull * 512 * 2;       //  1,572,864
  const size_t SZ_FL = 256;                     // 64 int flags
  const size_t NEED_FULL = SZ_XT + SZ_WH + SZ_FL;

  if (ws_size >= NEED_FULL) {
    u16* XT  = (u16*)ws;
    u16* Whi = (u16*)(ws + SZ_XT);
    int* FL  = (int*)(ws + SZ_XT + SZ_WH);
    k_prep<<<7168, 256, 0, stream>>>(X, W, XT, Whi, FL);
    k_fused<<<dim3(12, 64), 1024, 0, stream>>>(Whi, XT, out, FL);
    k_fix<<<64, 256, 0, stream>>>(X, W, FL, out);
  } else {
    k_exact<<<64, 256, 0, stream>>>(X, W, out);
  }
}

// Round 8
// 242.485 us; speedup vs baseline: 1.0642x; 1.0642x over previous
//
#include <hip/hip_runtime.h>

// LIF constants (match reference)
#define KOEFF 0.951229424500714f
#define K64   0.040762204f            // KOEFF^64
#define LOG2K (-0.07213475204444817f) // log2(KOEFF)

typedef unsigned short u16;
typedef __attribute__((ext_vector_type(8))) short short8;   // 8 bf16 (MFMA A/B frag)
typedef __attribute__((ext_vector_type(4))) float f32x4;    // MFMA C/D frag

__device__ __forceinline__ u16 f2bf(float f) {
  unsigned int v = __float_as_uint(f);
  unsigned int r = (v + 0x7FFFu + ((v >> 16) & 1u)) >> 16;
  return (u16)r;
}
__device__ __forceinline__ float bf2f(u16 u) {
  return __uint_as_float(((unsigned int)u) << 16);
}

// ---------------------------------------------------------------------------
// Kernel 1 (merged prep): blockIdx.x partitions three independent jobs:
//   [0,4096)      : X [64][512 j][512 t] fp32 -> XT16 [64][512 t][512 j] bf16
//   [4096,7168)   : W rows 512..2047 cols 0..511 -> bf16 Whi[1536][512]; zero flags
//   [7168,7744)   : WT2[j'][i'] = W[512+i'][512+j'] (recurrent block, transposed)
// ---------------------------------------------------------------------------
__global__ __launch_bounds__(256) void k_prep(const float* __restrict__ X, const float* __restrict__ W,
                                              u16* __restrict__ XT, u16* __restrict__ Whi,
                                              float* __restrict__ WT2, int* __restrict__ flags) {
  __shared__ float tile[64][65];
  const int blk = blockIdx.x;
  if (blk < 4096) {
    const int b  = blk >> 6;
    const int r2 = blk & 63;
    const int j0 = (r2 & 7) * 64;
    const int t0 = (r2 >> 3) * 64;
    const float* src = X + ((size_t)b * 512 + j0) * 512 + t0;
    for (int e = threadIdx.x; e < 64 * 16; e += 256) {
      int r = e >> 4, c = e & 15;
      float4 v = *(const float4*)(src + (size_t)r * 512 + c * 4);
      tile[r][c * 4 + 0] = v.x; tile[r][c * 4 + 1] = v.y;
      tile[r][c * 4 + 2] = v.z; tile[r][c * 4 + 3] = v.w;
    }
    __syncthreads();
    u16* dst = XT + ((size_t)b * 512 + t0) * 512 + j0;
    for (int e = threadIdx.x; e < 64 * 16; e += 256) {
      int tr = e >> 4, c = e & 15;
      ushort4 o;
      o.x = f2bf(tile[c * 4 + 0][tr]); o.y = f2bf(tile[c * 4 + 1][tr]);
      o.z = f2bf(tile[c * 4 + 2][tr]); o.w = f2bf(tile[c * 4 + 3][tr]);
      *(ushort4*)(dst + (size_t)tr * 512 + c * 4) = o;
    }
  } else if (blk < 7168) {
    if (blk == 4096 && threadIdx.x < 64) flags[threadIdx.x] = 0;
    int p = (blk - 4096) * 256 + threadIdx.x;
    int i = p >> 9, j = p & 511;
    Whi[p] = f2bf(W[(size_t)(512 + i) * 2048 + j]);
  } else {
    const int bx = blk - 7168;            // 0..575
    const int i0 = (bx / 24) * 64;
    const int j0 = (bx % 24) * 64;
    const float* src = W + (size_t)(512 + i0) * 2048 + 512 + j0;
    for (int e = threadIdx.x; e < 64 * 16; e += 256) {
      int r = e >> 4, c = e & 15;
      float4 v = *(const float4*)(src + (size_t)r * 2048 + c * 4);
      tile[r][c * 4 + 0] = v.x; tile[r][c * 4 + 1] = v.y;
      tile[r][c * 4 + 2] = v.z; tile[r][c * 4 + 3] = v.w;
    }
    __syncthreads();
    float* dst = WT2 + (size_t)j0 * 1536 + i0;
    for (int e = threadIdx.x; e < 64 * 16; e += 256) {
      int jr = e >> 4, c = e & 15;
      float4 o;
      o.x = tile[c * 4 + 0][jr]; o.y = tile[c * 4 + 1][jr];
      o.z = tile[c * 4 + 2][jr]; o.w = tile[c * 4 + 3][jr];
      *(float4*)(dst + (size_t)jr * 1536 + c * 4) = o;
    }
  }
}

// ---------------------------------------------------------------------------
// Kernel 2: U16[b][t][i'] = bf16( sum_j Whi[i'][j] * XT16[b][t][j] ), fused P.
// 256x256 tile, BK=64, 8 waves (2M x 4N), per-wave 128x64 output.
// Double-buffered LDS (2 x 64 KB), stage-ahead one K-tile, counted vmcnt(8)
// keeps next tile's 8 loads in flight across compute (T3/T4), raw s_barrier,
// setprio around MFMA clusters (T5), XOR-swizzled LDS via pre-swizzled global
// source (T2, rule #21). Epilogue: U store + per-chunk P partials (shfl tree).
// ---------------------------------------------------------------------------
__global__ __launch_bounds__(512, 2) void k_gemm(const u16* __restrict__ A,
                                                 const u16* __restrict__ Bx, u16* __restrict__ U,
                                                 float* __restrict__ P) {
  __shared__ u16 lA[2][256 * 64];   // 32 KB each buffer
  __shared__ u16 lB[2][256 * 64];
  const int b    = blockIdx.y;
  const int mt   = blockIdx.x >> 1;    // 0..5 (256-neuron tile)
  const int nt   = blockIdx.x & 1;     // 0..1 (256-t tile)
  const int tid  = threadIdx.x;        // 0..511
  const int wv   = tid >> 6;           // 0..7
  const int lane = tid & 63;
  const int tl   = lane & 15;
  const int qg   = lane >> 4;          // 0..3
  const int l7   = lane & 7;
  const int wr   = wv >> 2;            // m-half 0..1 (128 rows)
  const int wcn  = wv & 3;             // n-quarter 0..3 (64 t)

  f32x4 acc[8][4];
#pragma unroll
  for (int mi = 0; mi < 8; ++mi)
#pragma unroll
    for (int ni = 0; ni < 4; ++ni) acc[mi][ni] = (f32x4)0.0f;

  const u16* gA = A + (size_t)mt * 256 * 512;
  const u16* gB = Bx + ((size_t)b * 512 + nt * 256) * 512;

  // staging geometry: call a in 0..3 covers rows [a*64, a*64+64); thread's
  // row = a*64 + (tid>>3), 16B chunk = tid&7, source pre-swizzled (rule #21)
  const int srow = tid >> 3;
  const int ssw  = (((tid & 7) ^ (srow & 7)) << 3);

#define STAGE(ktv, dv)                                                          \
  do {                                                                          \
    const u16* sa_ = gA + (ktv) * 64;                                           \
    const u16* sb_ = gB + (ktv) * 64;                                           \
    _Pragma("unroll")                                                           \
    for (int a_ = 0; a_ < 4; ++a_)                                              \
      __builtin_amdgcn_global_load_lds(                                         \
          (const __attribute__((address_space(1))) void*)(sa_ + (size_t)(a_ * 64 + srow) * 512 + ssw), \
          (__attribute__((address_space(3))) void*)(&lA[dv][0] + a_ * 4096 + wv * 512), 16, 0, 0); \
    _Pragma("unroll")                                                           \
    for (int a_ = 0; a_ < 4; ++a_)                                              \
      __builtin_amdgcn_global_load_lds(                                         \
          (const __attribute__((address_space(1))) void*)(sb_ + (size_t)(a_ * 64 + srow) * 512 + ssw), \
          (__attribute__((address_space(3))) void*)(&lB[dv][0] + a_ * 4096 + wv * 512), 16, 0, 0); \
  } while (0)

  auto compute_tile = [&](int d) {
#pragma unroll
    for (int q = 0; q < 4; ++q) {
      const int mh = q & 1, nh = q >> 1;
      short8 ah[4][2], bb[2][2];
#pragma unroll
      for (int mi = 0; mi < 4; ++mi)
#pragma unroll
        for (int kk = 0; kk < 2; ++kk) {
          int row = wr * 128 + (mh * 4 + mi) * 16 + tl;
          ah[mi][kk] = *(const short8*)&lA[d][row * 64 + ((((kk << 2) | qg) ^ l7) << 3)];
        }
#pragma unroll
      for (int ni = 0; ni < 2; ++ni)
#pragma unroll
        for (int kk = 0; kk < 2; ++kk) {
          int row = wcn * 64 + (nh * 2 + ni) * 16 + tl;
          bb[ni][kk] = *(const short8*)&lB[d][row * 64 + ((((kk << 2) | qg) ^ l7) << 3)];
        }
      __builtin_amdgcn_s_setprio(1);
#pragma unroll
      for (int mi = 0; mi < 4; ++mi)
#pragma unroll
        for (int ni = 0; ni < 2; ++ni)
#pragma unroll
          for (int kk = 0; kk < 2; ++kk)
            acc[mh * 4 + mi][nh * 2 + ni] =
                __builtin_amdgcn_mfma_f32_16x16x32_bf16(ah[mi][kk], bb[ni][kk],
                                                        acc[mh * 4 + mi][nh * 2 + ni], 0, 0, 0);
      __builtin_amdgcn_s_setprio(0);
    }
  };

  // prologue: stage K-tile 0 into buf0
  STAGE(0, 0);
#pragma unroll
  for (int it = 0; it < 4; ++it) {
    {  // kt = 2*it, compute buf0, stage kt+1 -> buf1
      STAGE(2 * it + 1, 1);
      asm volatile("s_waitcnt vmcnt(8)" ::: "memory");   // kt's 8 landed; kt+1's 8 in flight
      __builtin_amdgcn_sched_barrier(0);
      __builtin_amdgcn_s_barrier();
      __builtin_amdgcn_sched_barrier(0);
      compute_tile(0);
      __builtin_amdgcn_sched_barrier(0);
      __builtin_amdgcn_s_barrier();                      // buf0 reads done -> reusable
    }
    {  // kt = 2*it+1, compute buf1, stage kt+1 -> buf0 (if any)
      if (it < 3) {
        STAGE(2 * it + 2, 0);
        asm volatile("s_waitcnt vmcnt(8)" ::: "memory");
      } else {
        asm volatile("s_waitcnt vmcnt(0)" ::: "memory");
      }
      __builtin_amdgcn_sched_barrier(0);
      __builtin_amdgcn_s_barrier();
      __builtin_amdgcn_sched_barrier(0);
      compute_tile(1);
      __builtin_amdgcn_sched_barrier(0);
      __builtin_amdgcn_s_barrier();
    }
  }
#undef STAGE

  // --- epilogue 1: U tile store (bf16). D layout: col=lane&15 (t), row=(lane>>4)*4+q (i)
#pragma unroll
  for (int mi = 0; mi < 8; ++mi) {
    int ib = mt * 256 + wr * 128 + mi * 16 + (qg << 2);
#pragma unroll
    for (int ni = 0; ni < 4; ++ni) {
      int t = nt * 256 + wcn * 64 + ni * 16 + tl;
      f32x4 v = acc[mi][ni];
      ushort4 o;
      o.x = f2bf(v.x); o.y = f2bf(v.y); o.z = f2bf(v.z); o.w = f2bf(v.w);
      *(ushort4*)(U + ((size_t)b * 512 + t) * 1536 + ib) = o;
    }
  }
  // --- epilogue 2: fused chunk partials. Wave's 64-t span = chunk c.
  {
    const int c = nt * 4 + wcn;
    float pv[8][4];
#pragma unroll
    for (int mi = 0; mi < 8; ++mi)
#pragma unroll
      for (int q = 0; q < 4; ++q) pv[mi][q] = 0.f;
#pragma unroll
    for (int ni = 0; ni < 4; ++ni) {
      float w = exp2f(LOG2K * (float)(63 - ni * 16 - tl));  // K^{63 - t_local}
#pragma unroll
      for (int mi = 0; mi < 8; ++mi) {
        f32x4 a = acc[mi][ni];
        pv[mi][0] = fmaf(w, a.x, pv[mi][0]);
        pv[mi][1] = fmaf(w, a.y, pv[mi][1]);
        pv[mi][2] = fmaf(w, a.z, pv[mi][2]);
        pv[mi][3] = fmaf(w, a.w, pv[mi][3]);
      }
    }
#pragma unroll
    for (int off = 1; off < 16; off <<= 1)
#pragma unroll
      for (int mi = 0; mi < 8; ++mi)
#pragma unroll
        for (int q = 0; q < 4; ++q)
          pv[mi][q] += __shfl_xor(pv[mi][q], off, 16);
    if (tl == 0) {
      float* pb = P + ((size_t)b * 8 + c) * 1536 + mt * 256 + wr * 128 + (qg << 2);
#pragma unroll
      for (int mi = 0; mi < 8; ++mi)
#pragma unroll
        for (int q = 0; q < 4; ++q) pb[mi * 16 + q] = pv[mi][q];
    }
  }
}

// ---------------------------------------------------------------------------
// Kernel 3: chunk walk over bf16 U, 2 neurons/thread (verbatim R6).
// ---------------------------------------------------------------------------
__global__ __launch_bounds__(256) void k_chunk(const u16* __restrict__ U, const float* __restrict__ P,
                                               float* __restrict__ out, int* __restrict__ flags) {
  const int g = blockIdx.x * 256 + threadIdx.x;   // 0..767
  const int i = g * 2;
  const int c = blockIdx.y, b = blockIdx.z;
  float s0 = 0.f, s1 = 0.f;
  const float* pp = P + (size_t)b * 8 * 1536 + i;
  for (int d = 0; d < c; ++d) {
    float2 pv = *(const float2*)(pp + (size_t)d * 1536);
    s0 = fmaf(s0, K64, pv.x);
    s1 = fmaf(s1, K64, pv.y);
  }
  const u16* up = U + ((size_t)b * 512 + c * 64) * 1536 + i;
  const bool wr = (i >= 1280);
  float* op = out + ((size_t)b * 256 + (i - 1280)) * 512 + c * 64;  // valid only if wr
  bool viol = false;
  unsigned int buf[8];
#pragma unroll
  for (int j = 0; j < 8; ++j) buf[j] = *(const unsigned int*)(up + (size_t)j * 1536);
  for (int t0 = 0; t0 < 64; t0 += 8) {
    float sp0[8], sp1[8];
#pragma unroll
    for (int j = 0; j < 8; ++j) {
      unsigned int u = buf[j];
      if (t0 + 8 < 64) buf[j] = *(const unsigned int*)(up + (size_t)(t0 + 8 + j) * 1536);
      s0 = fmaf(s0, KOEFF, bf2f((u16)(u & 0xffffu)));
      s1 = fmaf(s1, KOEFF, bf2f((u16)(u >> 16)));
      bool a = (s0 >= 1.0f), bsp = (s1 >= 1.0f);
      viol = viol || a || bsp || (s0 < -1.0f) || (s1 < -1.0f);
      sp0[j] = a ? 1.f : 0.f;
      sp1[j] = bsp ? 1.f : 0.f;
    }
    if (wr) {
      *(float4*)(op + t0)           = make_float4(sp0[0], sp0[1], sp0[2], sp0[3]);
      *(float4*)(op + t0 + 4)       = make_float4(sp0[4], sp0[5], sp0[6], sp0[7]);
      *(float4*)(op + 512 + t0)     = make_float4(sp1[0], sp1[1], sp1[2], sp1[3]);
      *(float4*)(op + 512 + t0 + 4) = make_float4(sp1[4], sp1[5], sp1[6], sp1[7]);
    }
  }
  if (viol) atomicOr(&flags[b], 1);
}

// ---------------------------------------------------------------------------
// Kernel 4: exact sequential scan (bf16 U), gated per batch (verbatim R6).
// ---------------------------------------------------------------------------
__global__ __launch_bounds__(768) void k_fix(const u16* __restrict__ U, const float* __restrict__ WT2,
                                             const int* __restrict__ flags, float* __restrict__ out) {
  const int b = blockIdx.x;
  if (flags[b] == 0) return;
  const int tid = threadIdx.x;
  const int wv = tid >> 6, lane = tid & 63;
  __shared__ unsigned long long spk[24];
  for (int w = tid; w < 24; w += 768) spk[w] = 0ULL;
  __syncthreads();
  float s0 = 0.f, s1 = 0.f, r0 = 0.f, r1 = 0.f;
  const int i0 = 2 * tid;
  const u16* ub = U + (size_t)b * 512 * 1536 + i0;
  unsigned int u = *(const unsigned int*)ub;
  for (int t = 0; t < 512; ++t) {
    unsigned int unext = u;
    if (t < 511) unext = *(const unsigned int*)(ub + (size_t)(t + 1) * 1536);
    float a0 = fmaf(s0, KOEFF, bf2f((u16)(u & 0xffffu)));
    float a1 = fmaf(s1, KOEFF, bf2f((u16)(u >> 16)));
    for (int wd = 0; wd < 24; ++wd) {
      unsigned long long m = spk[wd];
      while (m) {
        int bit = __ffsll(m) - 1;
        m &= m - 1;
        int jp = ((wd >> 1) << 7) + (bit << 1) + (wd & 1);
        float2 rv = *(const float2*)(WT2 + (size_t)jp * 1536 + i0);
        a0 += rv.x; a1 += rv.y;
      }
    }
    if (r0 > 0.f) a0 = 0.f;
    if (r1 > 0.f) a1 = 0.f;
    bool sp0 = a0 >= 1.0f, sp1 = a1 >= 1.0f;
    r0 -= 1.f; r1 -= 1.f;
    if (sp0) r0 = 2.f;
    if (sp1) r1 = 2.f;
    if (a0 < -1.f) a0 = -1.f;
    if (a1 < -1.f) a1 = -1.f;
    s0 = a0; s1 = a1;
    if (i0 >= 1280) {
      float* o = out + ((size_t)b * 256 + (i0 - 1280)) * 512 + t;
      o[0]   = sp0 ? 1.f : 0.f;
      o[512] = sp1 ? 1.f : 0.f;
    }
    __syncthreads();
    unsigned long long b0 = __ballot(sp0);
    unsigned long long b1 = __ballot(sp1);
    if (lane == 0) { spk[2 * wv] = b0; spk[2 * wv + 1] = b1; }
    __syncthreads();
    u = unext;
  }
}

// ---------------------------------------------------------------------------
// Fallback: WTF[j][i'] = W[512+i'][j] for all j in [0,2048)
// ---------------------------------------------------------------------------
__global__ __launch_bounds__(256) void k_wtf(const float* __restrict__ W, float* __restrict__ WTF) {
  __shared__ float tile[64][65];
  const int i0 = blockIdx.x * 64;
  const int j0 = blockIdx.y * 64;
  const float* src = W + (size_t)(512 + i0) * 2048 + j0;
  for (int e = threadIdx.x; e < 64 * 16; e += 256) {
    int r = e >> 4, c = e & 15;
    float4 v = *(const float4*)(src + (size_t)r * 2048 + c * 4);
    tile[r][c * 4 + 0] = v.x; tile[r][c * 4 + 1] = v.y;
    tile[r][c * 4 + 2] = v.z; tile[r][c * 4 + 3] = v.w;
  }
  __syncthreads();
  float* dst = WTF + (size_t)j0 * 1536 + i0;
  for (int e = threadIdx.x; e < 64 * 16; e += 256) {
    int jr = e >> 4, c = e & 15;
    float4 o;
    o.x = tile[c * 4 + 0][jr]; o.y = tile[c * 4 + 1][jr];
    o.z = tile[c * 4 + 2][jr]; o.w = tile[c * 4 + 3][jr];
    *(float4*)(dst + (size_t)jr * 1536 + c * 4) = o;
  }
}

// ---------------------------------------------------------------------------
// Fallback exact simulator (only when ws too small for fast path)
// ---------------------------------------------------------------------------
__global__ __launch_bounds__(256) void k_exact(const float* __restrict__ X, const float* __restrict__ W,
                                               const float* __restrict__ WTF, int use_wt,
                                               float* __restrict__ out) {
  const int b = blockIdx.x, tid = threadIdx.x;
  const int wv = tid >> 6, lane = tid & 63;
  float st[6], rf[6];
#pragma unroll
  for (int r = 0; r < 6; ++r) { st[r] = 0.f; rf[r] = 0.f; }
  __shared__ unsigned int mask[64];
  for (int w = tid; w < 64; w += 256) mask[w] = 0u;
  __syncthreads();
  for (int t = 0; t < 512; ++t) {
    {
      float x = X[((size_t)b * 512 + tid) * 512 + t];
      unsigned long long bl = __ballot(x > 0.5f);
      if (lane == 0) { mask[2 * wv] = (unsigned int)bl; mask[2 * wv + 1] = (unsigned int)(bl >> 32); }
      x = X[((size_t)b * 512 + 256 + tid) * 512 + t];
      bl = __ballot(x > 0.5f);
      if (lane == 0) { mask[8 + 2 * wv] = (unsigned int)bl; mask[9 + 2 * wv] = (unsigned int)(bl >> 32); }
    }
    __syncthreads();
    float add[6] = {0.f, 0.f, 0.f, 0.f, 0.f, 0.f};
    for (int wd = 0; wd < 64; ++wd) {
      unsigned int m = mask[wd];
      while (m) {
        int bitp = __ffs(m) - 1;
        m &= m - 1;
        int j = wd * 32 + bitp;
        if (use_wt) {
          const float* row = WTF + (size_t)j * 1536;
#pragma unroll
          for (int r = 0; r < 6; ++r) add[r] += row[tid + 256 * r];
        } else {
#pragma unroll
          for (int r = 0; r < 6; ++r) add[r] += W[(size_t)(512 + tid + 256 * r) * 2048 + j];
        }
      }
    }
    bool sp[6];
#pragma unroll
    for (int r = 0; r < 6; ++r) {
      float a = fmaf(st[r], KOEFF, add[r]);
      if (rf[r] > 0.f) a = 0.f;
      sp[r] = a >= 1.0f;
      rf[r] -= 1.f;
      if (sp[r]) rf[r] = 2.f;
      if (a < -1.f) a = -1.f;
      st[r] = a;
      int gi = 512 + tid + 256 * r;
      if (gi >= 1792) out[((size_t)b * 256 + (gi - 1792)) * 512 + t] = sp[r] ? 1.f : 0.f;
    }
    __syncthreads();
#pragma unroll
    for (int r = 0; r < 6; ++r) {
      unsigned long long bl = __ballot(sp[r]);
      if (lane == 0) {
        mask[16 + 8 * r + 2 * wv] = (unsigned int)bl;
        mask[17 + 8 * r + 2 * wv] = (unsigned int)(bl >> 32);
      }
    }
    __syncthreads();
  }
}

// ---------------------------------------------------------------------------
extern "C" void kernel_launch(void* const* d_in, const int* in_sizes, int n_in,
                              void* d_out, int out_size, void* d_ws, size_t ws_size,
                              hipStream_t stream) {
  const float* X = (const float*)d_in[0];   // [64][512][512]
  const float* W = (const float*)d_in[1];   // [2048][2048]
  float* out = (float*)d_out;               // [64][256][512]
  char* ws = (char*)d_ws;

  const size_t SZ_XT  = 64ull * 512 * 512 * 2;     //  33,554,432
  const size_t SZ_WH  = 1536ull * 512 * 2;         //   1,572,864
  const size_t SZ_WT2 = 1536ull * 1536 * 4;        //   9,437,184
  const size_t SZ_U   = 64ull * 512 * 1536 * 2;    // 100,663,296 (bf16)
  const size_t SZ_P   = 64ull * 8 * 1536 * 4;      //   3,145,728
  const size_t SZ_FL  = 256;                       // 64 int flags
  const size_t NEED_FULL = SZ_XT + SZ_WH + SZ_WT2 + SZ_U + SZ_P + SZ_FL;
  const size_t NEED_MID  = 2048ull * 1536 * 4;

  if (ws_size >= NEED_FULL) {
    u16*   XT  = (u16*)ws;
    u16*   Whi = (u16*)(ws + SZ_XT);
    float* WT2 = (float*)(ws + SZ_XT + SZ_WH);
    u16*   U   = (u16*)(ws + SZ_XT + SZ_WH + SZ_WT2);
    float* P   = (float*)(ws + SZ_XT + SZ_WH + SZ_WT2 + SZ_U);
    int*   FL  = (int*)(ws + SZ_XT + SZ_WH + SZ_WT2 + SZ_U + SZ_P);
    k_prep<<<7744, 256, 0, stream>>>(X, W, XT, Whi, WT2, FL);
    k_gemm<<<dim3(12, 64), 512, 0, stream>>>(Whi, XT, U, P);
    k_chunk<<<dim3(3, 8, 64), 256, 0, stream>>>(U, P, out, FL);
    k_fix<<<64, 768, 0, stream>>>(U, WT2, FL, out);
  } else if (ws_size >= NEED_MID) {
    float* WTF = (float*)ws;
    k_wtf<<<dim3(24, 32), 256, 0, stream>>>(W, WTF);
    k_exact<<<64, 256, 0, stream>>>(X, W, WTF, 1, out);
  } else {
    k_exact<<<64, 256, 0, stream>>>(X, W, nullptr, 0, out);
  }
}